// Round 12
// baseline (1375.928 us; speedup 1.0000x reference)
//
#include <hip/hip_runtime.h>
#include <hip/hip_cooperative_groups.h>

namespace cg = cooperative_groups;

#define NEG_FILL (-65535.0f)   // -2^16 + 1, the mask fill value
#define NSLOT 32

typedef __attribute__((ext_vector_type(8))) short  short8;   // 8 x bf16 bits
typedef __attribute__((ext_vector_type(4))) float  floatx4;  // mfma acc

__device__ inline unsigned short f2bf(float f) {             // f32 -> bf16 RNE
    unsigned u = __float_as_uint(f);
    u += 0x7FFFu + ((u >> 16) & 1u);
    return (unsigned short)(u >> 16);
}
__device__ inline float bf2f(unsigned short h) {
    return __uint_as_float(((unsigned)h) << 16);
}
__device__ __forceinline__ short8 pack8(float4 a, float4 b) {
    short8 f;
    f[0] = (short)f2bf(a.x); f[1] = (short)f2bf(a.y);
    f[2] = (short)f2bf(a.z); f[3] = (short)f2bf(a.w);
    f[4] = (short)f2bf(b.x); f[5] = (short)f2bf(b.y);
    f[6] = (short)f2bf(b.z); f[7] = (short)f2bf(b.w);
    return f;
}

// ---------------------------------------------------------------------------
// Masked softmax -> WsT (transposed weights in LDS), full 512 rows.
__device__ __forceinline__ void softmax_to_WsT(
    const float* __restrict__ Bc, int sl, int lane, int g,
    float (*WsT)[8]) {
    #pragma unroll
    for (int kk = 0; kk < 2; ++kk) {
        const int k = g + (kk << 2);
        float v[8];
        float mx = NEG_FILL;
        #pragma unroll
        for (int j = 0; j < 8; ++j) {
            int l = lane + (j << 6);
            v[j] = (l < sl) ? Bc[(k << 9) + l] : NEG_FILL;
            mx = fmaxf(mx, v[j]);
        }
        #pragma unroll
        for (int off = 32; off; off >>= 1) mx = fmaxf(mx, __shfl_xor(mx, off));
        float s = 0.f;
        #pragma unroll
        for (int j = 0; j < 8; ++j) { v[j] = expf(v[j] - mx); s += v[j]; }
        #pragma unroll
        for (int off = 32; off; off >>= 1) s += __shfl_xor(s, off);
        const float inv = 1.0f / s;
        #pragma unroll
        for (int j = 0; j < 8; ++j) WsT[lane + (j << 6)][k] = v[j] * inv;
    }
}

// delta = high @ ln^T via MFMA, batched loads, atomics into slot.
// Wave g covers rows [g*128, +128) — the same rows wave g wrote (wave-private).
__device__ __forceinline__ void delta_phase(
    const unsigned short* __restrict__ lnb, const unsigned short (*Hn)[64],
    float* __restrict__ slot, int g, int m, int q) {
    short8 afragH[2];                 // A[m=k_c][k=o], valid m < 8
    #pragma unroll
    for (int oh = 0; oh < 2; ++oh) {
        short8 f = {0, 0, 0, 0, 0, 0, 0, 0};
        if (m < 8) f = *(const short8*)&Hn[m][oh * 32 + q * 8];
        afragH[oh] = f;
    }
    #pragma unroll
    for (int half = 0; half < 2; ++half) {
        short8 bf[4][2];
        #pragma unroll
        for (int t2 = 0; t2 < 4; ++t2) {          // 8 loads in flight
            const int lt = (g << 7) + (((half << 2) + t2) << 4);
            const unsigned short* p = &lnb[((lt + m) << 6) + q * 8];
            bf[t2][0] = *(const short8*)p;
            bf[t2][1] = *(const short8*)(p + 32);
        }
        #pragma unroll
        for (int t2 = 0; t2 < 4; ++t2) {
            const int lt = (g << 7) + (((half << 2) + t2) << 4);
            floatx4 acc = {0.f, 0.f, 0.f, 0.f};
            acc = __builtin_amdgcn_mfma_f32_16x16x32_bf16(afragH[0], bf[t2][0], acc, 0, 0, 0);
            acc = __builtin_amdgcn_mfma_f32_16x16x32_bf16(afragH[1], bf[t2][1], acc, 0, 0, 0);
            if (q < 2) {
                #pragma unroll
                for (int r = 0; r < 4; ++r)
                    atomicAdd(&slot[(q * 4 + r) * 512 + lt + m], acc[r]);
            }
        }
    }
}

// T-phase (iterations 1/2): T = W @ ln with 8 independent 8B loads in flight;
// whole 32-row batches past seq_len skipped (their W is exactly 0). Returns
// the squashed high values for this thread's (g, lane) and (g+4, lane).
__device__ __forceinline__ void t_phase_squash(
    const unsigned short* __restrict__ lnb, int sl, int t, int lane,
    int g, int m, int q,
    float (*WsT)[8], float (*Tpart)[8][64], float (*Tred)[64],
    float& hf0, float& hf1) {
    floatx4 Tacc[8];
    #pragma unroll
    for (int k = 0; k < 8; ++k) Tacc[k] = (floatx4){0.f, 0.f, 0.f, 0.f};
    const int l0 = g << 7;
    const int rem = sl - l0;
    int nact = (rem <= 0) ? 0 : ((rem + 31) >> 5);
    if (nact > 4) nact = 4;

    for (int ii = 0; ii < nact; ++ii) {
        uint2 u[8];
        #pragma unroll
        for (int j = 0; j < 8; ++j) {
            const int l = l0 + (ii << 5) + (j << 2) + q;
            u[j] = *(const uint2*)&lnb[(l << 6) + (m << 2)];
        }
        #pragma unroll
        for (int j = 0; j < 8; ++j) {
            const int l = l0 + (ii << 5) + (j << 2) + q;
            const float x0 = __uint_as_float(u[j].x << 16);
            const float x1 = __uint_as_float(u[j].x & 0xFFFF0000u);
            const float x2 = __uint_as_float(u[j].y << 16);
            const float x3 = __uint_as_float(u[j].y & 0xFFFF0000u);
            const float4 wa = *(const float4*)&WsT[l][0];
            const float4 wb = *(const float4*)&WsT[l][4];
#define TROW(K, WV)                                          \
            Tacc[K][0] = fmaf(WV, x0, Tacc[K][0]);           \
            Tacc[K][1] = fmaf(WV, x1, Tacc[K][1]);           \
            Tacc[K][2] = fmaf(WV, x2, Tacc[K][2]);           \
            Tacc[K][3] = fmaf(WV, x3, Tacc[K][3]);
            TROW(0, wa.x) TROW(1, wa.y) TROW(2, wa.z) TROW(3, wa.w)
            TROW(4, wb.x) TROW(5, wb.y) TROW(6, wb.z) TROW(7, wb.w)
#undef TROW
        }
    }
    #pragma unroll
    for (int k = 0; k < 8; ++k)
        #pragma unroll
        for (int j = 0; j < 4; ++j) {
            float v = Tacc[k][j];
            v += __shfl_xor(v, 16);
            v += __shfl_xor(v, 32);
            Tacc[k][j] = v;
        }
    if (q == 0) {
        #pragma unroll
        for (int k = 0; k < 8; ++k)
            *(float4*)&Tpart[g][k][m << 2] =
                make_float4(Tacc[k][0], Tacc[k][1], Tacc[k][2], Tacc[k][3]);
    }
    __syncthreads();

    #pragma unroll
    for (int idx = t; idx < 512; idx += 256) {
        float s = (&Tpart[0][0][0])[idx] + (&Tpart[1][0][0])[idx]
                + (&Tpart[2][0][0])[idx] + (&Tpart[3][0][0])[idx];
        (&Tred[0][0])[idx] = s;
    }
    __syncthreads();

    float sq = 0.f;
    #pragma unroll
    for (int k = 0; k < 8; ++k) { float x = Tred[k][lane]; sq = fmaf(x, x, sq); }
    const float scale = sq / (1.0f + sq) / sqrtf(sq + 1e-9f);
    hf0 = scale * Tred[g][lane];
    hf1 = scale * Tred[g + 4][lane];
}

// ===========================================================================
// Persistent cooperative mega-kernel: whole 3-iteration routine, block b owns
// batch b throughout. Kernel boundaries -> grid.sync(); bred distributed
// (4 elems/block) with atomicExch (device-scope read+rezero, no stale-L1);
// Hn stays in LDS (no hout round-trip). grid = 1024 x 256, 4 blocks/CU
// co-resident (LDS 27.6 KB, VGPR ~64).
__global__ __launch_bounds__(256, 4) void k_all(
    const float* __restrict__ low,       // [1024,512,64] f32
    const float* __restrict__ S,         // [64,64] f32
    const float* __restrict__ Binit,     // [4096]
    const int* __restrict__ seq_len,     // [1024]
    unsigned short* __restrict__ ln,     // [1024,512,64] bf16 scratch
    float* __restrict__ slots,           // [NSLOT][4096]
    float* __restrict__ B1,              // [4096]
    float* __restrict__ B2,              // [4096]
    float* __restrict__ out)             // [1024,8,64] f32
{
    cg::grid_group grid = cg::this_grid();

    __shared__ __align__(16) float WsT[512][8];
    __shared__ __align__(16) float Tpart[4][8][64];
    __shared__ __align__(16) float Tred[8][64];
    __shared__ __align__(16) unsigned short Hn[8][64];

    const int t = threadIdx.x, lane = t & 63, g = t >> 6, b = blockIdx.x;
    const int m = lane & 15, q = lane >> 4;
    const int sl = seq_len[b];
    const float* lowb = low + ((size_t)b << 15);
    unsigned short* lnb = ln + ((size_t)b << 15);
    float* slot = slots + ((size_t)(b & (NSLOT - 1)) << 12);

    // zero this block's 128-float slice of slots (1024 x 128 = NSLOT*4096)
    if (t < 128) slots[(size_t)b * 128 + t] = 0.f;

    // ================= iteration 0: softmax(Binit); ln = low@S; T; squash ==
    softmax_to_WsT(Binit, sl, lane, g, WsT);
    __syncthreads();

    {   // B-frags for S: B[k=d][n=o]: o = nt*16+m, d = dh*32 + q*8 + j
        short8 sfrag[4][2];
        #pragma unroll
        for (int nt = 0; nt < 4; ++nt)
            #pragma unroll
            for (int dh = 0; dh < 2; ++dh) {
                short8 f;
                #pragma unroll
                for (int j = 0; j < 8; ++j) {
                    int d = dh * 32 + q * 8 + j;
                    f[j] = (short)f2bf(S[(d << 6) + nt * 16 + m]);
                }
                sfrag[nt][dh] = f;
            }

        float Tp[8][4];
        #pragma unroll
        for (int k = 0; k < 8; ++k)
            #pragma unroll
            for (int nt = 0; nt < 4; ++nt) Tp[k][nt] = 0.f;

        for (int tt = 0; tt < 8; ++tt) {
            const int lt = (g << 7) + (tt << 4);
            short8 afrag[2];              // A[m=l][k=d]
            #pragma unroll
            for (int dh = 0; dh < 2; ++dh) {
                const float4* p =
                    (const float4*)&lowb[((lt + m) << 6) + dh * 32 + q * 8];
                afrag[dh] = pack8(p[0], p[1]);
            }
            float lnr[4][4];              // [r][nt] bf16-rounded ln values
            #pragma unroll
            for (int nt = 0; nt < 4; ++nt) {
                floatx4 acc = {0.f, 0.f, 0.f, 0.f};
                acc = __builtin_amdgcn_mfma_f32_16x16x32_bf16(afrag[0], sfrag[nt][0], acc, 0, 0, 0);
                acc = __builtin_amdgcn_mfma_f32_16x16x32_bf16(afrag[1], sfrag[nt][1], acc, 0, 0, 0);
                // C: row = q*4+r (l-within-tile), col = nt*16+m (o)
                #pragma unroll
                for (int r = 0; r < 4; ++r) {
                    unsigned short hb = f2bf(acc[r]);
                    lnb[((size_t)(lt + (q << 2) + r) << 6) + nt * 16 + m] = hb;
                    lnr[r][nt] = bf2f(hb);     // numerics == stored ln
                }
            }
            #pragma unroll
            for (int r = 0; r < 4; ++r) {
                const int l = lt + (q << 2) + r;
                const float4 wa = *(const float4*)&WsT[l][0];
                const float4 wb = *(const float4*)&WsT[l][4];
                #pragma unroll
                for (int nt = 0; nt < 4; ++nt) {
                    const float x = lnr[r][nt];
                    Tp[0][nt] = fmaf(wa.x, x, Tp[0][nt]);
                    Tp[1][nt] = fmaf(wa.y, x, Tp[1][nt]);
                    Tp[2][nt] = fmaf(wa.z, x, Tp[2][nt]);
                    Tp[3][nt] = fmaf(wa.w, x, Tp[3][nt]);
                    Tp[4][nt] = fmaf(wb.x, x, Tp[4][nt]);
                    Tp[5][nt] = fmaf(wb.y, x, Tp[5][nt]);
                    Tp[6][nt] = fmaf(wb.z, x, Tp[6][nt]);
                    Tp[7][nt] = fmaf(wb.w, x, Tp[7][nt]);
                }
            }
        }
        // butterfly over q: sum the wave's 128 rows
        #pragma unroll
        for (int k = 0; k < 8; ++k)
            #pragma unroll
            for (int nt = 0; nt < 4; ++nt) {
                float v = Tp[k][nt];
                v += __shfl_xor(v, 16);
                v += __shfl_xor(v, 32);
                Tp[k][nt] = v;
            }
        #pragma unroll
        for (int k = 0; k < 8; ++k) Tpart[g][k][lane] = Tp[k][q];  // o = lane
        __syncthreads();

        #pragma unroll
        for (int idx = t; idx < 512; idx += 256) {
            float s = (&Tpart[0][0][0])[idx] + (&Tpart[1][0][0])[idx]
                    + (&Tpart[2][0][0])[idx] + (&Tpart[3][0][0])[idx];
            (&Tred[0][0])[idx] = s;
        }
        __syncthreads();

        float sq = 0.f;
        #pragma unroll
        for (int k = 0; k < 8; ++k) { float x = Tred[k][lane]; sq = fmaf(x, x, sq); }
        const float scale = sq / (1.0f + sq) / sqrtf(sq + 1e-9f);
        Hn[g][lane]     = f2bf(scale * Tred[g][lane]);
        Hn[g + 4][lane] = f2bf(scale * Tred[g + 4][lane]);
        __syncthreads();
    }

    __threadfence();
    grid.sync();                      // all slots zeroed grid-wide

    delta_phase(lnb, Hn, slot, g, m, q);

    __threadfence();
    grid.sync();                      // all delta-0 atomics done

    if (t < 4) {                      // bred: B1 = Binit + Σ slots (+ rezero)
        const int i = (b << 2) + t;
        float s = Binit[i];
        #pragma unroll
        for (int j = 0; j < NSLOT; ++j)
            s += atomicExch(&slots[j * 4096 + i], 0.f);
        B1[i] = s;
    }

    __threadfence();
    grid.sync();                      // B1 ready, slots rezeroed

    // ================= iteration 1: softmax(B1); T; squash; delta ==========
    softmax_to_WsT(B1, sl, lane, g, WsT);
    __syncthreads();
    {
        float hf0, hf1;
        t_phase_squash(lnb, sl, t, lane, g, m, q, WsT, Tpart, Tred, hf0, hf1);
        Hn[g][lane]     = f2bf(hf0);
        Hn[g + 4][lane] = f2bf(hf1);
        __syncthreads();
    }
    delta_phase(lnb, Hn, slot, g, m, q);

    __threadfence();
    grid.sync();                      // all delta-1 atomics done

    if (t < 4) {                      // bred: B2 = B1 + Σ slots (+ rezero)
        const int i = (b << 2) + t;
        float s = B1[i];
        #pragma unroll
        for (int j = 0; j < NSLOT; ++j)
            s += atomicExch(&slots[j * 4096 + i], 0.f);
        B2[i] = s;
    }

    __threadfence();
    grid.sync();                      // B2 ready

    // ================= iteration 2: softmax(B2); T; squash -> out ==========
    softmax_to_WsT(B2, sl, lane, g, WsT);
    __syncthreads();
    {
        float hf0, hf1;
        t_phase_squash(lnb, sl, t, lane, g, m, q, WsT, Tpart, Tred, hf0, hf1);
        out[(((size_t)b * 8 + g)     << 6) + lane] = hf0;
        out[(((size_t)b * 8 + g + 4) << 6) + lane] = hf1;
    }
}

// ===========================================================================
// R5-verified multi-kernel path (283 µs) — used if cooperative launch fails.
// ===========================================================================
__global__ __launch_bounds__(256) void k_init(const float* __restrict__ Binit,
                                              float* __restrict__ B0,
                                              float* __restrict__ slots) {
    int i = blockIdx.x * 256 + threadIdx.x;
    slots[i] = 0.f;
    if (i < 4096) B0[i] = Binit[i];
}

__global__ __launch_bounds__(256) void k_bred(const float* __restrict__ Bcur,
                                              float* __restrict__ Bnext,
                                              float* __restrict__ slots) {
    int i = blockIdx.x * 256 + threadIdx.x;       // 0..4095
    float s = Bcur[i];
    #pragma unroll
    for (int j = 0; j < NSLOT; ++j) {
        s += slots[j * 4096 + i];
        slots[j * 4096 + i] = 0.f;
    }
    Bnext[i] = s;
}

__global__ __launch_bounds__(256, 4) void k_lnT(
    const float* __restrict__ low, const float* __restrict__ S,
    const float* __restrict__ Bc, const int* __restrict__ seq_len,
    unsigned short* __restrict__ ln, float* __restrict__ hout)
{
    __shared__ __align__(16) float WsT[512][8];
    __shared__ __align__(16) float Tpart[4][8][64];
    __shared__ __align__(16) float Tred[8][64];

    const int t = threadIdx.x, lane = t & 63, g = t >> 6, b = blockIdx.x;
    const int m = lane & 15, q = lane >> 4;
    const int sl = seq_len[b];
    const float* lowb = low + ((size_t)b << 15);
    unsigned short* lnb = ln + ((size_t)b << 15);

    softmax_to_WsT(Bc, sl, lane, g, WsT);
    __syncthreads();

    short8 sfrag[4][2];
    #pragma unroll
    for (int nt = 0; nt < 4; ++nt)
        #pragma unroll
        for (int dh = 0; dh < 2; ++dh) {
            short8 f;
            #pragma unroll
            for (int j = 0; j < 8; ++j) {
                int d = dh * 32 + q * 8 + j;
                f[j] = (short)f2bf(S[(d << 6) + nt * 16 + m]);
            }
            sfrag[nt][dh] = f;
        }

    float Tp[8][4];
    #pragma unroll
    for (int k = 0; k < 8; ++k)
        #pragma unroll
        for (int nt = 0; nt < 4; ++nt) Tp[k][nt] = 0.f;

    for (int tt = 0; tt < 8; ++tt) {
        const int lt = (g << 7) + (tt << 4);
        short8 afrag[2];
        #pragma unroll
        for (int dh = 0; dh < 2; ++dh) {
            const float4* p =
                (const float4*)&lowb[((lt + m) << 6) + dh * 32 + q * 8];
            afrag[dh] = pack8(p[0], p[1]);
        }
        float lnr[4][4];
        #pragma unroll
        for (int nt = 0; nt < 4; ++nt) {
            floatx4 acc = {0.f, 0.f, 0.f, 0.f};
            acc = __builtin_amdgcn_mfma_f32_16x16x32_bf16(afrag[0], sfrag[nt][0], acc, 0, 0, 0);
            acc = __builtin_amdgcn_mfma_f32_16x16x32_bf16(afrag[1], sfrag[nt][1], acc, 0, 0, 0);
            #pragma unroll
            for (int r = 0; r < 4; ++r) {
                unsigned short hb = f2bf(acc[r]);
                lnb[((size_t)(lt + (q << 2) + r) << 6) + nt * 16 + m] = hb;
                lnr[r][nt] = bf2f(hb);
            }
        }
        #pragma unroll
        for (int r = 0; r < 4; ++r) {
            const int l = lt + (q << 2) + r;
            const float4 wa = *(const float4*)&WsT[l][0];
            const float4 wb = *(const float4*)&WsT[l][4];
            #pragma unroll
            for (int nt = 0; nt < 4; ++nt) {
                const float x = lnr[r][nt];
                Tp[0][nt] = fmaf(wa.x, x, Tp[0][nt]);
                Tp[1][nt] = fmaf(wa.y, x, Tp[1][nt]);
                Tp[2][nt] = fmaf(wa.z, x, Tp[2][nt]);
                Tp[3][nt] = fmaf(wa.w, x, Tp[3][nt]);
                Tp[4][nt] = fmaf(wb.x, x, Tp[4][nt]);
                Tp[5][nt] = fmaf(wb.y, x, Tp[5][nt]);
                Tp[6][nt] = fmaf(wb.z, x, Tp[6][nt]);
                Tp[7][nt] = fmaf(wb.w, x, Tp[7][nt]);
            }
        }
    }
    #pragma unroll
    for (int k = 0; k < 8; ++k)
        #pragma unroll
        for (int nt = 0; nt < 4; ++nt) {
            float v = Tp[k][nt];
            v += __shfl_xor(v, 16);
            v += __shfl_xor(v, 32);
            Tp[k][nt] = v;
        }
    #pragma unroll
    for (int k = 0; k < 8; ++k) Tpart[g][k][lane] = Tp[k][q];
    __syncthreads();

    #pragma unroll
    for (int idx = t; idx < 512; idx += 256) {
        float s = (&Tpart[0][0][0])[idx] + (&Tpart[1][0][0])[idx]
                + (&Tpart[2][0][0])[idx] + (&Tpart[3][0][0])[idx];
        (&Tred[0][0])[idx] = s;
    }
    __syncthreads();

    float sq = 0.f;
    #pragma unroll
    for (int k = 0; k < 8; ++k) { float x = Tred[k][lane]; sq = fmaf(x, x, sq); }
    const float scale = sq / (1.0f + sq) / sqrtf(sq + 1e-9f);
    hout[((size_t)b << 9) + (g << 6) + lane]       = scale * Tred[g][lane];
    hout[((size_t)b << 9) + ((g + 4) << 6) + lane] = scale * Tred[g + 4][lane];
}

__global__ __launch_bounds__(256, 4) void k_T(
    const unsigned short* __restrict__ ln, const float* __restrict__ Bc,
    const int* __restrict__ seq_len, float* __restrict__ hout)
{
    __shared__ __align__(16) float WsT[512][8];
    __shared__ __align__(16) float Tpart[4][8][64];
    __shared__ __align__(16) float Tred[8][64];

    const int t = threadIdx.x, lane = t & 63, g = t >> 6, b = blockIdx.x;
    const int m = lane & 15, q = lane >> 4;
    const int sl = seq_len[b];
    const unsigned short* lnb = ln + ((size_t)b << 15);

    softmax_to_WsT(Bc, sl, lane, g, WsT);
    __syncthreads();

    float hf0, hf1;
    t_phase_squash(lnb, sl, t, lane, g, m, q, WsT, Tpart, Tred, hf0, hf1);
    hout[((size_t)b << 9) + (g << 6) + lane]       = hf0;
    hout[((size_t)b << 9) + ((g + 4) << 6) + lane] = hf1;
}

__global__ __launch_bounds__(256, 8) void k_delta(
    const unsigned short* __restrict__ ln, const float* __restrict__ hout,
    float* __restrict__ slots)
{
    const int t = threadIdx.x, lane = t & 63, g = t >> 6;
    const int bb = blockIdx.x, b = bb >> 1, half = bb & 1;
    const int m = lane & 15, q = lane >> 4;
    const unsigned short* lnb = ln + ((size_t)b << 15);
    const float* hb = hout + ((size_t)b << 9);
    float* slot = slots + ((size_t)(b & (NSLOT - 1)) << 12);

    short8 afragH[2];
    #pragma unroll
    for (int oh = 0; oh < 2; ++oh) {
        short8 f = {0, 0, 0, 0, 0, 0, 0, 0};
        if (m < 8) {
            const float4* p = (const float4*)&hb[(m << 6) + oh * 32 + q * 8];
            f = pack8(p[0], p[1]);
        }
        afragH[oh] = f;
    }
    const int lbase = (half << 8) + (g << 6);
    #pragma unroll
    for (int pp = 0; pp < 2; ++pp) {
        short8 bf[2][2];
        #pragma unroll
        for (int u = 0; u < 2; ++u) {
            const int lt = lbase + (((pp << 1) + u) << 4);
            const unsigned short* p = &lnb[((lt + m) << 6) + q * 8];
            bf[u][0] = *(const short8*)p;
            bf[u][1] = *(const short8*)(p + 32);
        }
        #pragma unroll
        for (int u = 0; u < 2; ++u) {
            const int lt = lbase + (((pp << 1) + u) << 4);
            floatx4 acc = {0.f, 0.f, 0.f, 0.f};
            acc = __builtin_amdgcn_mfma_f32_16x16x32_bf16(afragH[0], bf[u][0], acc, 0, 0, 0);
            acc = __builtin_amdgcn_mfma_f32_16x16x32_bf16(afragH[1], bf[u][1], acc, 0, 0, 0);
            if (q < 2) {
                #pragma unroll
                for (int r = 0; r < 4; ++r)
                    atomicAdd(&slot[((q << 2) + r) * 512 + lt + m], acc[r]);
            }
        }
    }
}

// ---------------------------------------------------------------------------
extern "C" void kernel_launch(void* const* d_in, const int* in_sizes, int n_in,
                              void* d_out, int out_size, void* d_ws, size_t ws_size,
                              hipStream_t stream) {
    const float* low   = (const float*)d_in[0];   // [1024,512,64]
    const float* Binit = (const float*)d_in[1];   // [1,8,512]
    const float* S     = (const float*)d_in[2];   // [64,64]
    const int*   seq   = (const int*)d_in[3];     // [1024,1]
    float* outp = (float*)d_out;                  // [1024,8,64] f32

    const size_t LN_BYTES   = (size_t)1024 * 512 * 64 * 2;        // 67.1 MB
    const size_t SLOT_BYTES = (size_t)NSLOT * 4096 * sizeof(float);
    const size_t NEED = LN_BYTES + SLOT_BYTES + 2 * 4096 * sizeof(float);

    if (ws_size >= NEED) {
        unsigned short* lnw = (unsigned short*)d_ws;
        float* slots = (float*)((char*)d_ws + LN_BYTES);
        float* B1 = slots + (size_t)NSLOT * 4096;
        float* B2 = B1 + 4096;

        // --- preferred: single persistent cooperative kernel ---
        void* args[] = {(void*)&low, (void*)&S, (void*)&Binit, (void*)&seq,
                        (void*)&lnw, (void*)&slots, (void*)&B1, (void*)&B2,
                        (void*)&outp};
        hipError_t e = hipLaunchCooperativeKernel(
            (const void*)k_all, dim3(1024), dim3(256), args, 0, stream);
        if (e == hipSuccess) return;
        (void)hipGetLastError();      // clear; fall back to R5 path

        // --- fallback: R5-verified multi-kernel path (283 µs) ---
        k_init<<<(NSLOT * 4096) / 256, 256, 0, stream>>>(Binit, B1, slots);
        k_lnT<<<1024, 256, 0, stream>>>(low, S, B1, seq, lnw, outp);
        k_delta<<<2048, 256, 0, stream>>>(lnw, outp, slots);
        k_bred<<<16, 256, 0, stream>>>(B1, B2, slots);
        k_T<<<1024, 256, 0, stream>>>(lnw, B2, seq, outp);
        k_delta<<<2048, 256, 0, stream>>>(lnw, outp, slots);
        k_bred<<<16, 256, 0, stream>>>(B2, B1, slots);
        k_T<<<1024, 256, 0, stream>>>(lnw, B1, seq, outp);
    }
}